// Round 12
// baseline (2180.728 us; speedup 1.0000x reference)
//
#include <hip/hip_runtime.h>
#include <hip/hip_fp16.h>
#include <cstdint>
#include <cstddef>

typedef _Float16 f16;
typedef _Float16 f16x2 __attribute__((ext_vector_type(2)));
typedef _Float16 f16x4 __attribute__((ext_vector_type(4)));
typedef _Float16 f16x8 __attribute__((ext_vector_type(8)));
typedef int i32x4 __attribute__((ext_vector_type(4)));
typedef float f32x4 __attribute__((ext_vector_type(4)));

#define S_LEN 2048
#define BATCH 64
#define I_DIM 128
#define H_DIM 512
#define O_DIM 64

// ---------------------------------------------------------------------------
// Phase 1: u = x @ Wih via mfma_f32_16x16x32_f16.  (unchanged from R10/R11 —
// passed, absmax 0.0078; this A/B/D lane mapping is hardware-verified.)
// ---------------------------------------------------------------------------
__global__ __launch_bounds__(256)
void u_gemm_kernel(const float* __restrict__ x, const float* __restrict__ Wih,
                   f16* __restrict__ u) {
    const int tid = threadIdx.x;
    const int lane = tid & 63;
    const int w = tid >> 6;               // wave 0..3
    const int li = lane & 15;
    const int g = lane >> 4;              // 0..3
    const size_t r0 = (size_t)blockIdx.x * 64;
    const int c0 = blockIdx.y * 128;

    // bT[c][k]: transposed Wih tile, 128x128 f16, XOR-swizzled k slots.
    __shared__ __align__(16) f16 bT[128 * 128];

#pragma unroll
    for (int i = 0; i < 64; ++i) {
        int idx = i * 256 + tid;
        int k = idx >> 7;
        int c = idx & 127;
        float v = Wih[(size_t)k * H_DIM + c0 + c];
        bT[c * 128 + (k ^ ((c & 7) << 3))] = (f16)v;
    }

    const int tr = (int)r0 + w * 16 + li;
    f16x8 a[4];
#pragma unroll
    for (int kt = 0; kt < 4; ++kt) {
        const float* xp = x + (size_t)tr * I_DIM + kt * 32 + g * 8;
        f32x4 v0 = *(const f32x4*)(xp);
        f32x4 v1 = *(const f32x4*)(xp + 4);
        f16x8 h;
        h[0] = (f16)v0[0]; h[1] = (f16)v0[1]; h[2] = (f16)v0[2]; h[3] = (f16)v0[3];
        h[4] = (f16)v1[0]; h[5] = (f16)v1[1]; h[6] = (f16)v1[2]; h[7] = (f16)v1[3];
        a[kt] = h;
    }
    __syncthreads();

    f32x4 acc[8];
#pragma unroll
    for (int n = 0; n < 8; ++n) acc[n] = (f32x4){0.f, 0.f, 0.f, 0.f};

#pragma unroll
    for (int kt = 0; kt < 4; ++kt) {
#pragma unroll
        for (int n = 0; n < 8; ++n) {
            const int c = n * 16 + li;
            const int koff = (kt * 32 + g * 8) ^ ((c & 7) << 3);
            f16x8 b = *(const f16x8*)(&bT[c * 128 + koff]);
            acc[n] = __builtin_amdgcn_mfma_f32_16x16x32_f16(a[kt], b, acc[n], 0, 0, 0);
        }
    }

#pragma unroll
    for (int n = 0; n < 8; ++n) {
#pragma unroll
        for (int r = 0; r < 4; ++r) {
            size_t row = r0 + w * 16 + g * 4 + r;
            u[row * H_DIM + c0 + n * 16 + li] = (f16)acc[n][r];
        }
    }
}

// ---------------------------------------------------------------------------
// Phase 2: scan via int8 MFMA with FORCED direct-AGPR operands.
//
// R11 diagnosis: step = 1753cy, matrix pipe 1017cy (58% active-CU MfmaUtil),
// VALU 475cy (27%) vs ~160cy of honest source VALU. The excess matches the
// compiler copying AGPR-parked wf[] B-fragments to VGPRs before each MFMA
// (~128 v_accvgpr_read/step). Fix: inline-asm v_mfma_i32_16x16x64_i8 with
// "a" constraints on B and the accumulators -> MFMA reads AGPRs natively
// (ISA 10: A,B from VGPR or AGPR), zero copies. Budget: AGPR 144 (wf 128 +
// acc 16) + arch ~80 fits the 256/wave at 2 waves/SIMD (accum_offset is
// 4-granular, asymmetric splits legal). Integer math bit-identical.
// Hazard hygiene: s_nop x2 + sched_barrier(0) before reading acc (rule 18).
//
// Everything else verbatim R11 (passed, absmax 0.0078, scan 1496us):
// replicated-A h operand, deferred global h-store, per-column i8 quant.
// ---------------------------------------------------------------------------
__global__ __launch_bounds__(512, 2)
void rnn_scan_kernel(const float* __restrict__ Wrec, f16* __restrict__ uhs) {
    const int tid = threadIdx.x;          // 0..511
    const int b = blockIdx.x;
    const int l = tid & 63;
    const int w = tid >> 6;               // wave 0..7
    const int grp = l >> 4;               // 0..3
    const int li = l & 15;

    __shared__ __align__(16) signed char h8[2][512];   // double-buffered h (i8)
    __shared__ float colmax[512];

    // ---- pass 1: per-column max, coalesced (thread tid scans column tid) ----
    {
        const float* wp = Wrec + tid;
        float m0 = 0.f, m1 = 0.f, m2 = 0.f, m3 = 0.f;
        for (int k = 0; k < 512; k += 4) {
            m0 = fmaxf(m0, __builtin_fabsf(wp[(size_t)(k + 0) * H_DIM]));
            m1 = fmaxf(m1, __builtin_fabsf(wp[(size_t)(k + 1) * H_DIM]));
            m2 = fmaxf(m2, __builtin_fabsf(wp[(size_t)(k + 2) * H_DIM]));
            m3 = fmaxf(m3, __builtin_fabsf(wp[(size_t)(k + 3) * H_DIM]));
        }
        float m = fmaxf(fmaxf(m0, m1), fmaxf(m2, m3));
        colmax[tid] = fmaxf(m, 1e-20f);
    }
    h8[0][tid] = 0;                       // zero h buffer 0 (512 threads cover)
    __syncthreads();

    // ---- pass 2: quantize + pack W into B-fragments (forced to AGPR by
    // the "a" constraints at every use below) ----
    i32x4 wf[8][4];   // 128 AGPRs
#pragma unroll
    for (int j = 0; j < 4; ++j) {
        const int col = w * 64 + j * 16 + li;
        const float* wp = Wrec + col;
        const float sc = 127.f / colmax[col];
#pragma unroll
        for (int kt = 0; kt < 8; ++kt) {
            int wd0 = 0, wd1 = 0, wd2 = 0, wd3 = 0;
#pragma unroll
            for (int jj = 0; jj < 16; ++jj) {
                float v = wp[(size_t)(kt * 64 + grp * 16 + jj) * H_DIM] * sc;
                v = fminf(fmaxf(v, -127.f), 127.f);
                int q = ((int)rintf(v)) & 255;
                int sh = 8 * (jj & 3);
                if (jj < 4)       wd0 |= q << sh;
                else if (jj < 8)  wd1 |= q << sh;
                else if (jj < 12) wd2 |= q << sh;
                else              wd3 |= q << sh;
            }
            i32x4 f; f.x = wd0; f.y = wd1; f.z = wd2; f.w = wd3;
            wf[kt][j] = f;
        }
    }

    // this thread's output column: c = w*64 + grp*16 + li == tid (j = grp)
    f16* io = uhs + (size_t)b * S_LEN * H_DIM + tid;
    const float inv = colmax[tid] * (1.f / 16129.f);   // colmax[c]/127^2

    float hp = 0.f;
    f16 hh_prev = (f16)0.f;               // deferred-store buffer
    float uc = (float)io[0];
    f16 ua = (f16)0.f;
    if (S_LEN > 1) ua = io[H_DIM];

    __syncthreads();

    for (int t = 0; t < S_LEN; ++t) {
        // deferred store of h(t-1): issued after the barrier that ended step
        // t-1 so its L2-commit retires during this step's compute.
        if (t > 0) io[(size_t)(t - 1) * H_DIM] = hh_prev;

        // prefetch u(t+2)
        f16 ub = (f16)0.f;
        if (t + 2 < S_LEN) ub = io[(size_t)(t + 2) * H_DIM];

        const signed char* hb = h8[t & 1];
        // A-frags: h8[kt*64 + grp*16 .. +15], broadcast within 16-lane group.
        i32x4 av[8];
#pragma unroll
        for (int kt = 0; kt < 8; ++kt)
            av[kt] = *(const i32x4*)(hb + kt * 64 + grp * 16);

        i32x4 a0 = {0, 0, 0, 0}, a1 = {0, 0, 0, 0};
        i32x4 a2 = {0, 0, 0, 0}, a3 = {0, 0, 0, 0};
#pragma unroll
        for (int kt = 0; kt < 8; ++kt) {
            // D,A,B,C operand order; A ("v") = h frag, B ("a") = wf, C=D ("+a").
            asm("v_mfma_i32_16x16x64_i8 %0, %2, %3, %0\n\t"
                "v_mfma_i32_16x16x64_i8 %1, %2, %4, %1"
                : "+a"(a0), "+a"(a1)
                : "v"(av[kt]), "a"(wf[kt][0]), "a"(wf[kt][1]));
            asm("v_mfma_i32_16x16x64_i8 %0, %2, %3, %0\n\t"
                "v_mfma_i32_16x16x64_i8 %1, %2, %4, %1"
                : "+a"(a2), "+a"(a3)
                : "v"(av[kt]), "a"(wf[kt][2]), "a"(wf[kt][3]));
        }
        // MFMA-write -> VALU-read-of-acc hazard gap (rule 18: fence + nops).
        asm volatile("s_nop 7\n\ts_nop 7");
        __builtin_amdgcn_sched_barrier(0);

        // replicated-A: all D rows equal -> reg 0 of tile j=grp is lane's z
        int zi = grp == 0 ? a0[0] : grp == 1 ? a1[0] : grp == 2 ? a2[0] : a3[0];
        float z = (float)zi * inv + uc;

        // tanh(z) = 1 - 2/(exp(2z)+1)
        float e2 = __expf(2.f * z);
        float r = 1.f - 2.f * __builtin_amdgcn_rcpf(e2 + 1.f);
        hp = 0.8f * hp + 0.2f * r;
        f16 hh = (f16)hp;

        h8[(t + 1) & 1][tid] = (signed char)(int)rintf(hp * 127.f);
        hh_prev = hh;                     // global store happens next iteration

        uc = (float)ua;
        ua = ub;
        __syncthreads();
    }
    io[(size_t)(S_LEN - 1) * H_DIM] = hh_prev;   // epilogue: last h
}

// ---------------------------------------------------------------------------
// Phase 3: out = hs @ Who via mfma_f32_16x16x32_f16. (unchanged from R11 —
// passed; memory-bound, ~25us floor.)
// ---------------------------------------------------------------------------
__global__ __launch_bounds__(256)
void out_gemm_kernel(const f16* __restrict__ hs, const float* __restrict__ Who,
                     float* __restrict__ out) {
    const int tid = threadIdx.x;
    const int lane = tid & 63;
    const int w = tid >> 6;               // wave 0..3
    const int li = lane & 15;
    const int g = lane >> 4;              // 0..3
    const size_t r0 = (size_t)blockIdx.x * 64;

    __shared__ __align__(16) f16 bT[64 * 512];   // 64 KB

#pragma unroll 4
    for (int i = 0; i < 128; ++i) {
        int idx = i * 256 + tid;
        int k = idx >> 6;
        int c = idx & 63;
        float v = Who[(size_t)k * O_DIM + c];
        bT[c * 512 + (k ^ ((c & 7) << 3))] = (f16)v;
    }

    const size_t tr = r0 + w * 16 + li;
    const f16* ap = hs + tr * H_DIM + g * 8;

    __syncthreads();

    f32x4 acc[4];
#pragma unroll
    for (int n = 0; n < 4; ++n) acc[n] = (f32x4){0.f, 0.f, 0.f, 0.f};

#pragma unroll
    for (int kt = 0; kt < 16; ++kt) {
        f16x8 a = *(const f16x8*)(ap + kt * 32);
#pragma unroll
        for (int n = 0; n < 4; ++n) {
            const int c = n * 16 + li;
            const int koff = (kt * 32 + g * 8) ^ ((c & 7) << 3);
            f16x8 b = *(const f16x8*)(&bT[c * 512 + koff]);
            acc[n] = __builtin_amdgcn_mfma_f32_16x16x32_f16(a, b, acc[n], 0, 0, 0);
        }
    }

#pragma unroll
    for (int n = 0; n < 4; ++n) {
#pragma unroll
        for (int r = 0; r < 4; ++r) {
            size_t row = r0 + w * 16 + g * 4 + r;
            out[row * O_DIM + n * 16 + li] = acc[n][r];
        }
    }
}

extern "C" void kernel_launch(void* const* d_in, const int* in_sizes, int n_in,
                              void* d_out, int out_size, void* d_ws, size_t ws_size,
                              hipStream_t stream) {
    const float* x    = (const float*)d_in[0];   // [64][2048][128]
    const float* Wih  = (const float*)d_in[1];   // [128][512]
    const float* Wrec = (const float*)d_in[2];   // [512][512]
    const float* Who  = (const float*)d_in[3];   // [512][64]
    float* out = (float*)d_out;                  // [64][2048][64]
    f16* uhs = (f16*)d_ws;                       // 128 MB: u, then hs in-place

    const int R = BATCH * S_LEN;

    u_gemm_kernel<<<dim3(R / 64, H_DIM / 128), 256, 0, stream>>>(x, Wih, uhs);
    rnn_scan_kernel<<<dim3(BATCH), 512, 0, stream>>>(Wrec, uhs);
    out_gemm_kernel<<<dim3(R / 64), 256, 0, stream>>>(uhs, Who, out);
}